// Round 5
// baseline (457.753 us; speedup 1.0000x reference)
//
#include <hip/hip_runtime.h>
#include <hip/hip_bf16.h>
#include <stdint.h>

// Problem constants
#define B_   32
#define N_   480
#define DIM_ 1024
#define H_   16
#define D_   64
#define M_   (B_*N_)   // 15360
#define BH_  (B_*H_)   // 512

typedef __bf16 bf16;
typedef __bf16 bf16x4 __attribute__((ext_vector_type(4)));
typedef __bf16 bf16x8 __attribute__((ext_vector_type(8)));
typedef short  short4v __attribute__((ext_vector_type(4)));
typedef float  f32x4  __attribute__((ext_vector_type(4)));

// async global->LDS, 16B per lane; LDS dest = wave-uniform base + lane*16
__device__ __forceinline__ void gld_lds16(const void* g, void* l) {
    using GP = const __attribute__((address_space(1))) unsigned int*;
    using LP = __attribute__((address_space(3))) unsigned int*;
    __builtin_amdgcn_global_load_lds((GP)(uintptr_t)g, (LP)(unsigned int)(uintptr_t)l, 16, 0, 0);
}

// ---------------- fp32 -> bf16 converts ----------------
__global__ void cvt4(const float* __restrict__ in, bf16* __restrict__ out, int n4) {
    int i = blockIdx.x * 256 + threadIdx.x;
    if (i >= n4) return;
    float4 v = ((const float4*)in)[i];
    bf16x4 o = { (bf16)v.x, (bf16)v.y, (bf16)v.z, (bf16)v.w };
    ((bf16x4*)out)[i] = o;
}

__global__ void cvtW(const float* __restrict__ Wq, const float* __restrict__ Wk,
                     const float* __restrict__ Wv, const float* __restrict__ Wo,
                     bf16* __restrict__ Wcat, bf16* __restrict__ Wob) {
    int i = blockIdx.x * 256 + threadIdx.x;
    const float* src; bf16* dst;
    switch (blockIdx.y) {
        case 0: src = Wq; dst = Wcat;                break;
        case 1: src = Wk; dst = Wcat + DIM_*DIM_;    break;
        case 2: src = Wv; dst = Wcat + 2*DIM_*DIM_;  break;
        default: src = Wo; dst = Wob;                break;
    }
    float4 v = ((const float4*)src)[i];
    bf16x4 o = { (bf16)v.x, (bf16)v.y, (bf16)v.z, (bf16)v.w };
    ((bf16x4*)dst)[i] = o;
}

// ======== shared GEMM core: 128x128 tile, BK=64, XOR-swizzled LDS ========
#define GEMM_PRE()                                                            \
    const int tid  = threadIdx.x;                                             \
    const int lane = tid & 63;                                                \
    const int wid  = tid >> 6;                                                \
    const int wm   = wid & 1, wn = wid >> 1;                                  \
    const int m0   = blockIdx.y * 128;                                        \
    const int n0   = blockIdx.x * 128;                                        \
    const int lm   = lane & 15, lq = lane >> 4;                               \
    const int aLane = (lane >> 3) * 1024 + (((lane & 7) ^ (lane >> 3)) & 7) * 8; \
    const bf16* Asrc = A  + (m0 + wid*32) * 1024 + aLane;                     \
    const bf16* Bsrc = Bw + (n0 + wid*32) * 1024 + aLane;                     \
    bf16* AsDst = As + (wid*32)*64;                                           \
    bf16* BsDst = Bs + (wid*32)*64;                                           \
    int rowA[4], rowB[4];                                                     \
    _Pragma("unroll") for (int m = 0; m < 4; ++m) rowA[m] = (wm*64 + m*16 + lm)*64; \
    _Pragma("unroll") for (int n = 0; n < 4; ++n) rowB[n] = (wn*64 + n*16 + lm)*64; \
    const int sw = lm & 7;                                                    \
    int phys[2];                                                              \
    phys[0] = ((lq)     ^ sw) * 8;                                            \
    phys[1] = ((4 + lq) ^ sw) * 8;

#define GEMM_KLOOP(FIRST, SECOND)                                             \
    for (int k0 = 0; k0 < 1024; k0 += 64) {                                   \
        _Pragma("unroll") for (int j = 0; j < 4; ++j) {                       \
            gld_lds16(Asrc + k0 + j*8192, AsDst + j*512);                     \
            gld_lds16(Bsrc + k0 + j*8192, BsDst + j*512);                     \
        }                                                                     \
        __syncthreads();                                                      \
        _Pragma("unroll") for (int ks = 0; ks < 2; ++ks) {                    \
            bf16x8 af[4], bfr[4];                                             \
            _Pragma("unroll") for (int m = 0; m < 4; ++m)                     \
                af[m]  = *(const bf16x8*)&As[rowA[m] + phys[ks]];             \
            _Pragma("unroll") for (int n = 0; n < 4; ++n)                     \
                bfr[n] = *(const bf16x8*)&Bs[rowB[n] + phys[ks]];             \
            _Pragma("unroll") for (int m = 0; m < 4; ++m)                     \
                _Pragma("unroll") for (int n = 0; n < 4; ++n)                 \
                    acc[m][n] = __builtin_amdgcn_mfma_f32_16x16x32_bf16(      \
                        FIRST, SECOND, acc[m][n], 0, 0, 0);                   \
        }                                                                     \
        __syncthreads();                                                      \
    }

// ---------------- QKV projection GEMM ----------------
__global__ __launch_bounds__(256) void gemm_qkv(const bf16* __restrict__ A, const bf16* __restrict__ Bw,
                                                bf16* __restrict__ Qp, bf16* __restrict__ Kp,
                                                bf16* __restrict__ Vt) {
    __shared__ bf16 As[128*64];
    __shared__ bf16 Bs[128*64];
    GEMM_PRE();
    const int part = n0 >> 10;  // 0=Q,1=K,2=V (block-uniform)
    f32x4 acc[4][4] = {};

    if (part != 2) {
        GEMM_KLOOP(af[m], bfr[n]);
        bf16* dst = (part == 0) ? Qp : Kp;
        int hh[4], dd[4];
#pragma unroll
        for (int n = 0; n < 4; ++n) {
            int rem = (n0 + wn*64 + n*16 + lm) & 1023;
            hh[n] = rem >> 6; dd[n] = rem & 63;
        }
#pragma unroll
        for (int m = 0; m < 4; ++m) {
#pragma unroll
            for (int r = 0; r < 4; ++r) {
                int gm = m0 + wm*64 + m*16 + lq*4 + r;
                int b  = gm / 480;
                int nn = gm - b*480;
#pragma unroll
                for (int n = 0; n < 4; ++n)
                    dst[((b*16 + hh[n])*480 + nn)*64 + dd[n]] = (bf16)acc[m][n][r];
            }
        }
    } else {
        GEMM_KLOOP(bfr[n], af[m]);
#pragma unroll
        for (int m = 0; m < 4; ++m) {
            int gmBase = m0 + wm*64 + m*16;
            int b  = gmBase / 480;
            int nn = gmBase - b*480 + lm;
#pragma unroll
            for (int n = 0; n < 4; ++n)
#pragma unroll
                for (int r = 0; r < 4; ++r) {
                    int rem = (n0 + wn*64 + n*16 + lq*4 + r) & 1023;
                    int h = rem >> 6, d = rem & 63;
                    Vt[((b*16 + h)*64 + d)*480 + nn] = (bf16)acc[m][n][r];
                }
        }
    }
}

// ---------------- fused attention v5 ----------------
// Back to 16 q/wave (R3 residency) + R4's zero-conflict strides + register-
// prefetch pipeline: K/V global loads for kt+1 issue after barrier 2 and are
// consumed by the LDS store at the top of kt+1 -> HBM latency hides under
// compute. 384 thr (6 waves), q-tile 96, grid (5,512)=2560 blocks.
#define KT 96
#define KS_LD 68    // 136B rows: zero conflicts (measured R4)
#define VS_LD 100   // 200B rows: zero conflicts (measured R4)
__global__ __launch_bounds__(384) void attn(const bf16* __restrict__ Qp, const bf16* __restrict__ Kp,
                                            const bf16* __restrict__ Vt, const float* __restrict__ pe,
                                            bf16* __restrict__ O) {
    __shared__ bf16 Sm[KT*KS_LD + 64*VS_LD];   // Ks | Vs; reused as Os in epilogue
    bf16* Ks = Sm;
    bf16* Vs = Sm + KT*KS_LD;
    const int tid  = threadIdx.x;
    const int lane = tid & 63, wid = tid >> 6;
    const int bh   = blockIdx.y;
    const int b    = bh >> 4, h = bh & 15;
    const int qblk = blockIdx.x * 96;
    const int lm   = lane & 15, lq = lane >> 4;
    const int qbase = bh * (N_ * 64);

    // staging coords (uniform: 768 chunks / 384 threads = 2 each)
    const int kRow0 = tid >> 3,          kOff0 = (tid & 7) * 8;
    const int kRow1 = (tid + 384) >> 3,  kOff1 = kOff0;
    const int vRow0 = tid / 12,          vOff0 = (tid % 12) * 8;
    const int vRow1 = (tid + 384) / 12,  vOff1 = ((tid + 384) % 12) * 8;

    // Q fragments as B-operand (n=q=lm, k=d=lq*8+j)
    bf16x8 qb[2];
#pragma unroll
    for (int ks = 0; ks < 2; ++ks)
        qb[ks] = *(const bf16x8*)&Qp[qbase + (qblk + wid*16 + lm)*64 + ks*32 + lq*8];
    const float* peRow = pe + (qblk + wid*16 + lm)*480;

    f32x4 ot[4] = {};
    float lsum = 0.f;

    // prefetch kt=0 into registers
    uint4 kr0, kr1, vr0, vr1;
    kr0 = *(const uint4*)&Kp[qbase + kRow0*64 + kOff0];
    kr1 = *(const uint4*)&Kp[qbase + kRow1*64 + kOff1];
    vr0 = *(const uint4*)&Vt[qbase + vRow0*480 + vOff0];
    vr1 = *(const uint4*)&Vt[qbase + vRow1*480 + vOff1];

#pragma unroll
    for (int kt = 0; kt < 5; ++kt) {
        __syncthreads();   // prior iter's LDS reads done
        *(uint4*)&Ks[kRow0*KS_LD + kOff0] = kr0;
        *(uint4*)&Ks[kRow1*KS_LD + kOff1] = kr1;
        *(uint4*)&Vs[vRow0*VS_LD + vOff0] = vr0;
        *(uint4*)&Vs[vRow1*VS_LD + vOff1] = vr1;
        __syncthreads();
        if (kt < 4) {      // issue next tile's loads; waited on at next store
            int kb = qbase + (kt+1)*KT*64;
            int vb = qbase + (kt+1)*KT;
            kr0 = *(const uint4*)&Kp[kb + kRow0*64 + kOff0];
            kr1 = *(const uint4*)&Kp[kb + kRow1*64 + kOff1];
            vr0 = *(const uint4*)&Vt[vb + vRow0*480 + vOff0];
            vr1 = *(const uint4*)&Vt[vb + vRow1*480 + vOff1];
        }

        // S^T = K Q^T; P^T = exp(scale*S^T + pe) packed as 16x16x16 B-frags
        short4v pb[6];
#pragma unroll
        for (int mf = 0; mf < 6; ++mf) {
            f32x4 s = {};
#pragma unroll
            for (int ks = 0; ks < 2; ++ks) {
                bf16x8 ka = *(const bf16x8*)&Ks[(mf*16 + lm)*KS_LD + ks*32 + lq*8];
                s = __builtin_amdgcn_mfma_f32_16x16x32_bf16(ka, qb[ks], s, 0, 0, 0);
            }
            f32x4 pv4 = *(const f32x4*)&peRow[kt*KT + mf*16 + lq*4];
            bf16x4 pv;
#pragma unroll
            for (int r = 0; r < 4; ++r) {
                float e = __expf(s[r] * 0.125f + pv4[r]);
                lsum += e;
                pv[r] = (bf16)e;
            }
            pb[mf] = __builtin_bit_cast(short4v, pv);
        }

        // O^T += V^T P^T via 16x16x16 (A = V frags straight from Vs rows)
#pragma unroll
        for (int df = 0; df < 4; ++df)
#pragma unroll
            for (int mf = 0; mf < 6; ++mf) {
                short4v va = *(const short4v*)&Vs[(df*16 + lm)*VS_LD + mf*16 + lq*4];
                ot[df] = __builtin_amdgcn_mfma_f32_16x16x16bf16_1k(va, pb[mf], ot[df], 0, 0, 0);
            }
    }

    // softmax denom across the 4 lane-groups holding q=lm
    lsum += __shfl_xor(lsum, 16);
    lsum += __shfl_xor(lsum, 32);
    float rl = 1.f / lsum;

    // transpose O^T -> O via LDS (overlay), coalesced 16B stores
    __syncthreads();
    bf16* Os = Sm;  // [96 q][KS_LD]
#pragma unroll
    for (int df = 0; df < 4; ++df) {
        bf16x4 v;
#pragma unroll
        for (int r = 0; r < 4; ++r) v[r] = (bf16)(ot[df][r] * rl);
        *(bf16x4*)&Os[(wid*16 + lm)*KS_LD + df*16 + lq*4] = v;
    }
    __syncthreads();
#pragma unroll
    for (int p = 0; p < 2; ++p) {
        int c = p*384 + tid;
        int row = c >> 3, d0 = (c & 7) * 8;
        uint4 u = *(const uint4*)&Os[row*KS_LD + d0];
        *(uint4*)&O[(b*480 + qblk + row)*1024 + h*64 + d0] = u;
    }
}

// ---------------- output projection GEMM + bias ----------------
__global__ __launch_bounds__(256) void gemm_out(const bf16* __restrict__ A, const bf16* __restrict__ Bw,
                                                const float* __restrict__ bo, float* __restrict__ out) {
    __shared__ bf16 As[128*64];
    __shared__ bf16 Bs[128*64];
    GEMM_PRE();
    f32x4 acc[4][4] = {};
    GEMM_KLOOP(af[m], bfr[n]);
#pragma unroll
    for (int m = 0; m < 4; ++m)
#pragma unroll
        for (int n = 0; n < 4; ++n)
#pragma unroll
            for (int r = 0; r < 4; ++r) {
                int gm = m0 + wm*64 + m*16 + lq*4 + r;
                int gn = n0 + wn*64 + n*16 + lm;
                out[gm*1024 + gn] = acc[m][n][r] + bo[gn];
            }
}

// ---------------- launcher ----------------
extern "C" void kernel_launch(void* const* d_in, const int* in_sizes, int n_in,
                              void* d_out, int out_size, void* d_ws, size_t ws_size,
                              hipStream_t stream) {
    const float* q  = (const float*)d_in[0];
    const float* Wq = (const float*)d_in[1];
    const float* Wk = (const float*)d_in[2];
    const float* Wv = (const float*)d_in[3];
    const float* pe = (const float*)d_in[4];
    const float* Wo = (const float*)d_in[5];
    const float* bo = (const float*)d_in[6];
    float* out = (float*)d_out;

    char* ws = (char*)d_ws;
    bf16* Abf  = (bf16*)(ws);                         // q bf16 (M x 1024); reused as attn O buffer
    bf16* Wcat = (bf16*)(ws + 31457280);              // 3072 x 1024
    bf16* Wob  = (bf16*)(ws + 31457280 + 6291456);    // 1024 x 1024
    bf16* Qp   = (bf16*)(ws + 39845888);              // [bh][n][d]
    bf16* Kp   = (bf16*)(ws + 71303168);              // [bh][n][d]
    bf16* Vt   = (bf16*)(ws + 102760448);             // [bh][d][n]

    cvt4<<<(M_*DIM_/4 + 255)/256, 256, 0, stream>>>(q, Abf, M_*DIM_/4);
    cvtW<<<dim3(DIM_*DIM_/4/256, 4), 256, 0, stream>>>(Wq, Wk, Wv, Wo, Wcat, Wob);

    gemm_qkv<<<dim3(24, 120), 256, 0, stream>>>(Abf, Wcat, Qp, Kp, Vt);
    attn<<<dim3(5, 512), 384, 0, stream>>>(Qp, Kp, Vt, pe, Abf);
    gemm_out<<<dim3(8, 120), 256, 0, stream>>>(Abf, Wob, bo, out);
}